// Round 12
// baseline (277.537 us; speedup 1.0000x reference)
//
#include <hip/hip_runtime.h>
#include <hip/hip_bf16.h>

#define N_NODES 50000
#define N_EDGES 800000
#define SLOTS 48           // fixed per-node edge region; Poisson(16) tail: P(deg>48) ~ 1e-12
#define FILL_U4 600000     // 50000*48 ints / 4 per uint4
#define FILL_BLOCKS 2344   // ceil(600000/256)
#define DEG_BLOCKS 196     // ceil(50000/256)

typedef __attribute__((ext_vector_type(8))) short bf16x8;
typedef __attribute__((ext_vector_type(4))) float f32x4;

__device__ __forceinline__ float bf2f(unsigned short u) {
    unsigned int x = ((unsigned int)u) << 16;
    return __uint_as_float(x);
}
__device__ __forceinline__ unsigned short f2bf(float f) {
    unsigned int x = __float_as_uint(f);
    unsigned int lsb = (x >> 16) & 1u;
    x += 0x7fffu + lsb;
    return (unsigned short)(x >> 16);
}
__device__ __forceinline__ unsigned int packbf(float lo, float hi) {
    return ((unsigned int)f2bf(hi) << 16) | (unsigned int)f2bf(lo);
}

// ---- prep: W frags + features->bf16 + zero-rows + edge_slots prefill + deg zero ----
#define NF2 3125   // 800000 uint4 conversions / 256
__global__ __launch_bounds__(256) void k_prep(
        const float* __restrict__ Ws0, const float* __restrict__ Wn0,
        const float* __restrict__ Ws1, const float* __restrict__ Wn1,
        const float* __restrict__ Ws2, const float* __restrict__ Wn2,
        __hip_bfloat16* __restrict__ frag0, __hip_bfloat16* __restrict__ frag1,
        __hip_bfloat16* __restrict__ frag2,
        const float* __restrict__ fin, unsigned int* __restrict__ fout,
        unsigned int* __restrict__ z1, unsigned int* __restrict__ z2,
        unsigned int* __restrict__ zt,
        int* __restrict__ edge_src, int* __restrict__ deg) {
    int b = blockIdx.x;
    if (b >= 40 + NF2 + 1 + FILL_BLOCKS) {  // zero per-node degree counters
        int n = (b - (40 + NF2 + 1 + FILL_BLOCKS)) * 256 + threadIdx.x;
        if (n < N_NODES) deg[n] = 0;
        return;
    }
    if (b >= 40 + NF2 + 1) {  // prefill edge_src slots with zero-row index N_NODES
        int i = (b - (40 + NF2 + 1)) * 256 + threadIdx.x;
        if (i < FILL_U4) {
            uint4 v = {N_NODES, N_NODES, N_NODES, N_NODES};
            ((uint4*)edge_src)[i] = v;
        }
        return;
    }
    if (b >= 40 + NF2) {  // gather zero-rows (row N_NODES of fbf,h1,h2,t2)
        int tid = threadIdx.x;
        if (tid < 64)       fout[(size_t)N_NODES * 64 + tid] = 0;
        else if (tid < 128) z1[(size_t)N_NODES * 64 + (tid - 64)] = 0;
        else if (tid < 192) z2[(size_t)N_NODES * 64 + (tid - 128)] = 0;
        else if (tid < 224) zt[(size_t)N_NODES * 32 + (tid - 192)] = 0;  // t2 row (64 bf16)
        return;
    }
    if (b >= 40) {  // features fp32 -> bf16, 8 floats -> uint4 per thread
        int i = (b - 40) * 256 + threadIdx.x;   // i < 800000
        const float4* f4 = (const float4*)fin;
        float4 a = f4[2 * i];
        float4 c = f4[2 * i + 1];
        uint4 o;
        o.x = packbf(a.x, a.y);
        o.y = packbf(a.z, a.w);
        o.z = packbf(c.x, c.y);
        o.w = packbf(c.z, c.w);
        ((uint4*)fout)[i] = o;
        return;
    }
    const float* Wself;
    const float* Wneigh;
    __hip_bfloat16* frag;
    int Dout, lb;
    if (b < 16)      { Wself = Ws0; Wneigh = Wn0; frag = frag0; Dout = 128; lb = b; }
    else if (b < 32) { Wself = Ws1; Wneigh = Wn1; frag = frag1; Dout = 128; lb = b - 16; }
    else             { Wself = Ws2; Wneigh = Wn2; frag = frag2; Dout = 64;  lb = b - 32; }
    int t = lb * 256 + threadIdx.x;
    int nCt = Dout >> 4;
    int total = nCt * 8 * 64;
    if (t >= total) return;
    int lane = t & 63;
    int kt = (t >> 6) & 7;
    int ct = t >> 9;
    int q = lane >> 4;
    int n = ct * 16 + (lane & 15);
    unsigned short* dstp = (unsigned short*)frag + ((size_t)((ct * 8 + kt) * 64 + lane)) * 8;
    #pragma unroll
    for (int j = 0; j < 8; ++j) {
        int k = kt * 32 + q * 8 + j;
        float v = (k < 128) ? Wself[k * Dout + n] : Wneigh[(k - 128) * Dout + n];
        dstp[j] = f2bf(v);
    }
}

// ---- direct CSR scatter: one atomic slot-claim per edge ----
__global__ __launch_bounds__(256) void k_scatter(const int* __restrict__ src,
                                                 const int* __restrict__ dst,
                                                 int* __restrict__ deg,
                                                 int* __restrict__ edge_src) {
    int e = blockIdx.x * 256 + threadIdx.x;
    if (e >= N_EDGES) return;
    int d = dst[e];
    int p = atomicAdd(&deg[d], 1);
    if (p < SLOTS) edge_src[d * SLOTS + p] = src[e];
}

// ---- per-node offsets from degrees ----
__global__ __launch_bounds__(256) void k_nodes(const int* __restrict__ deg,
                                               int* __restrict__ off_beg,
                                               int* __restrict__ off_end,
                                               float* __restrict__ inv_deg) {
    int n = blockIdx.x * 256 + threadIdx.x;
    if (n >= N_NODES) return;
    int v = min(deg[n], SLOTS);
    off_beg[n] = n * SLOTS;
    off_end[n] = n * SLOTS + ((v + 15) & ~15);      // padded span; pad slots hold N_NODES
    inv_deg[n] = 1.0f / (float)max(v, 1);
}

// ---------------- mean aggregation, 128-dim rows (R2-verified structure) ----------------
__global__ void k_agg(const __hip_bfloat16* __restrict__ hv,
                      const int* __restrict__ off_beg, const int* __restrict__ off_end,
                      const int* __restrict__ edge_src, const float* __restrict__ inv_deg,
                      __hip_bfloat16* __restrict__ msg) {
    int gid = blockIdx.x * blockDim.x + threadIdx.x;
    int node = gid >> 6;
    int lane = gid & 63;
    if (node >= N_NODES) return;
    int quad = lane >> 4;   // which edge within a group of 4
    int sub = lane & 15;    // 16B column chunk
    int beg = off_beg[node], endp = off_end[node];  // span multiple of 16
    const uint4* hp = (const uint4*)hv;  // 16 uint4 per row

    float a0[8], a1[8], a2[8], a3[8];
    #pragma unroll
    for (int c = 0; c < 8; ++c) { a0[c] = 0.f; a1[c] = 0.f; a2[c] = 0.f; a3[c] = 0.f; }

    for (int i = beg; i < endp; i += 16) {
        int s0 = edge_src[i + quad];
        int s1 = edge_src[i + 4 + quad];
        int s2 = edge_src[i + 8 + quad];
        int s3 = edge_src[i + 12 + quad];
        uint4 u0 = hp[(size_t)s0 * 16 + sub];
        uint4 u1 = hp[(size_t)s1 * 16 + sub];
        uint4 u2 = hp[(size_t)s2 * 16 + sub];
        uint4 u3 = hp[(size_t)s3 * 16 + sub];
        a0[0] += bf2f((unsigned short)(u0.x & 0xffffu)); a0[1] += bf2f((unsigned short)(u0.x >> 16));
        a0[2] += bf2f((unsigned short)(u0.y & 0xffffu)); a0[3] += bf2f((unsigned short)(u0.y >> 16));
        a0[4] += bf2f((unsigned short)(u0.z & 0xffffu)); a0[5] += bf2f((unsigned short)(u0.z >> 16));
        a0[6] += bf2f((unsigned short)(u0.w & 0xffffu)); a0[7] += bf2f((unsigned short)(u0.w >> 16));
        a1[0] += bf2f((unsigned short)(u1.x & 0xffffu)); a1[1] += bf2f((unsigned short)(u1.x >> 16));
        a1[2] += bf2f((unsigned short)(u1.y & 0xffffu)); a1[3] += bf2f((unsigned short)(u1.y >> 16));
        a1[4] += bf2f((unsigned short)(u1.z & 0xffffu)); a1[5] += bf2f((unsigned short)(u1.z >> 16));
        a1[6] += bf2f((unsigned short)(u1.w & 0xffffu)); a1[7] += bf2f((unsigned short)(u1.w >> 16));
        a2[0] += bf2f((unsigned short)(u2.x & 0xffffu)); a2[1] += bf2f((unsigned short)(u2.x >> 16));
        a2[2] += bf2f((unsigned short)(u2.y & 0xffffu)); a2[3] += bf2f((unsigned short)(u2.y >> 16));
        a2[4] += bf2f((unsigned short)(u2.z & 0xffffu)); a2[5] += bf2f((unsigned short)(u2.z >> 16));
        a2[6] += bf2f((unsigned short)(u2.w & 0xffffu)); a2[7] += bf2f((unsigned short)(u2.w >> 16));
        a3[0] += bf2f((unsigned short)(u3.x & 0xffffu)); a3[1] += bf2f((unsigned short)(u3.x >> 16));
        a3[2] += bf2f((unsigned short)(u3.y & 0xffffu)); a3[3] += bf2f((unsigned short)(u3.y >> 16));
        a3[4] += bf2f((unsigned short)(u3.z & 0xffffu)); a3[5] += bf2f((unsigned short)(u3.z >> 16));
        a3[6] += bf2f((unsigned short)(u3.w & 0xffffu)); a3[7] += bf2f((unsigned short)(u3.w >> 16));
    }

    float r[8];
    #pragma unroll
    for (int c = 0; c < 8; ++c) {
        float t = a0[c] + a1[c] + a2[c] + a3[c];
        t += __shfl_xor(t, 16);
        t += __shfl_xor(t, 32);
        r[c] = t;
    }
    if (quad == 0) {
        float w = inv_deg[node];
        uint4 o;
        o.x = ((unsigned int)f2bf(r[1] * w) << 16) | (unsigned int)f2bf(r[0] * w);
        o.y = ((unsigned int)f2bf(r[3] * w) << 16) | (unsigned int)f2bf(r[2] * w);
        o.z = ((unsigned int)f2bf(r[5] * w) << 16) | (unsigned int)f2bf(r[4] * w);
        o.w = ((unsigned int)f2bf(r[7] * w) << 16) | (unsigned int)f2bf(r[6] * w);
        ((uint4*)msg)[(size_t)node * 16 + sub] = o;
    }
}

// ---------------- mean aggregation, 64-dim rows (layer 3 transform-first) ----------------
__global__ void k_agg64(const __hip_bfloat16* __restrict__ tv,
                        const int* __restrict__ off_beg, const int* __restrict__ off_end,
                        const int* __restrict__ edge_src, const float* __restrict__ inv_deg,
                        float* __restrict__ g) {
    int gid = blockIdx.x * blockDim.x + threadIdx.x;
    int node = gid >> 6;
    int lane = gid & 63;
    if (node >= N_NODES) return;
    int oct = lane >> 3;    // edge slot 0..7
    int sub8 = lane & 7;    // 16B chunk within 128B row
    int beg = off_beg[node], endp = off_end[node];  // span multiple of 16
    const uint4* tp = (const uint4*)tv;  // 8 uint4 per 128B row

    float a0[8], a1[8];
    #pragma unroll
    for (int c = 0; c < 8; ++c) { a0[c] = 0.f; a1[c] = 0.f; }

    for (int i = beg; i < endp; i += 16) {
        int s0 = edge_src[i + oct];
        int s1 = edge_src[i + 8 + oct];
        uint4 u0 = tp[(size_t)s0 * 8 + sub8];
        uint4 u1 = tp[(size_t)s1 * 8 + sub8];
        a0[0] += bf2f((unsigned short)(u0.x & 0xffffu)); a0[1] += bf2f((unsigned short)(u0.x >> 16));
        a0[2] += bf2f((unsigned short)(u0.y & 0xffffu)); a0[3] += bf2f((unsigned short)(u0.y >> 16));
        a0[4] += bf2f((unsigned short)(u0.z & 0xffffu)); a0[5] += bf2f((unsigned short)(u0.z >> 16));
        a0[6] += bf2f((unsigned short)(u0.w & 0xffffu)); a0[7] += bf2f((unsigned short)(u0.w >> 16));
        a1[0] += bf2f((unsigned short)(u1.x & 0xffffu)); a1[1] += bf2f((unsigned short)(u1.x >> 16));
        a1[2] += bf2f((unsigned short)(u1.y & 0xffffu)); a1[3] += bf2f((unsigned short)(u1.y >> 16));
        a1[4] += bf2f((unsigned short)(u1.z & 0xffffu)); a1[5] += bf2f((unsigned short)(u1.z >> 16));
        a1[6] += bf2f((unsigned short)(u1.w & 0xffffu)); a1[7] += bf2f((unsigned short)(u1.w >> 16));
    }

    float r[8];
    #pragma unroll
    for (int c = 0; c < 8; ++c) {
        float t = a0[c] + a1[c];
        t += __shfl_xor(t, 8);    // reduce over the 8 oct groups (lane bits 3..5)
        t += __shfl_xor(t, 16);
        t += __shfl_xor(t, 32);
        r[c] = t;
    }
    if (oct == 0) {  // lanes 0..7 each write 8 fp32 (their 16B bf16 chunk -> 32B fp32)
        float w = inv_deg[node];
        float4 o1 = {r[0] * w, r[1] * w, r[2] * w, r[3] * w};
        float4 o2 = {r[4] * w, r[5] * w, r[6] * w, r[7] * w};
        ((float4*)g)[(size_t)node * 16 + sub8 * 2]     = o1;
        ((float4*)g)[(size_t)node * 16 + sub8 * 2 + 1] = o2;
    }
}

// ---------------- fused GEMM + bias (+ relu + l2norm), layers 1-2 ----------------
template <int NCT, bool LAST>
__global__ __launch_bounds__(256) void k_gemm(const __hip_bfloat16* __restrict__ Aself,
                                              const __hip_bfloat16* __restrict__ Aneigh,
                                              const __hip_bfloat16* __restrict__ frag,
                                              const float* __restrict__ bias,
                                              void* __restrict__ out_) {
    constexpr int Dout = NCT * 16;
    int tid = threadIdx.x;
    int wv = tid >> 6, lane = tid & 63;
    int n0 = blockIdx.x * 64 + wv * 16;
    if (n0 >= N_NODES) return;
    int q = lane >> 4, l15 = lane & 15;
    int rowA = n0 + l15;
    if (rowA > N_NODES - 1) rowA = N_NODES - 1;

    f32x4 acc[NCT];
    #pragma unroll
    for (int c = 0; c < NCT; ++c) acc[c] = (f32x4){0.f, 0.f, 0.f, 0.f};

    const bf16x8* fragv = (const bf16x8*)frag;
    #pragma unroll
    for (int kt = 0; kt < 8; ++kt) {
        int kb = (kt & 3) * 32 + q * 8;
        const __hip_bfloat16* Ab = (kt < 4) ? Aself : Aneigh;
        bf16x8 a = *(const bf16x8*)(Ab + (size_t)rowA * 128 + kb);
        #pragma unroll
        for (int ct = 0; ct < NCT; ++ct) {
            bf16x8 b = fragv[(ct * 8 + kt) * 64 + lane];
            acc[ct] = __builtin_amdgcn_mfma_f32_16x16x32_bf16(a, b, acc[ct], 0, 0, 0);
        }
    }

    float ss[4] = {0.f, 0.f, 0.f, 0.f};
    #pragma unroll
    for (int ct = 0; ct < NCT; ++ct) {
        float bc = bias[ct * 16 + l15];
        #pragma unroll
        for (int r = 0; r < 4; ++r) {
            float v = acc[ct][r] + bc;
            if (!LAST) v = fmaxf(v, 0.0f);
            acc[ct][r] = v;
            ss[r] += v * v;
        }
    }

    float scale[4];
    #pragma unroll
    for (int r = 0; r < 4; ++r) {
        if (!LAST) {
            float s = ss[r];
            s += __shfl_xor(s, 1);
            s += __shfl_xor(s, 2);
            s += __shfl_xor(s, 4);
            s += __shfl_xor(s, 8);
            scale[r] = 1.0f / fmaxf(sqrtf(s), 1e-12f);
        } else {
            scale[r] = 1.0f;
        }
    }

    #pragma unroll
    for (int ct = 0; ct < NCT; ++ct) {
        #pragma unroll
        for (int r = 0; r < 4; ++r) {
            int row = n0 + q * 4 + r;
            if (row < N_NODES) {
                float v = acc[ct][r] * scale[r];
                if (LAST)
                    ((float*)out_)[(size_t)row * Dout + ct * 16 + l15] = v;
                else
                    ((unsigned short*)out_)[(size_t)row * Dout + ct * 16 + l15] = f2bf(v);
            }
        }
    }
}

// ---------------- layer-3 pre-transform: t2 = h2 @ W_neigh2 (bf16 out, no epilogue) ----------------
__global__ __launch_bounds__(256) void k_gemmT(const __hip_bfloat16* __restrict__ h,
                                               const __hip_bfloat16* __restrict__ frag,
                                               __hip_bfloat16* __restrict__ t_out) {
    int tid = threadIdx.x;
    int wv = tid >> 6, lane = tid & 63;
    int n0 = blockIdx.x * 64 + wv * 16;
    if (n0 >= N_NODES) return;
    int q = lane >> 4, l15 = lane & 15;
    int rowA = n0 + l15;
    if (rowA > N_NODES - 1) rowA = N_NODES - 1;

    f32x4 acc[4];
    #pragma unroll
    for (int c = 0; c < 4; ++c) acc[c] = (f32x4){0.f, 0.f, 0.f, 0.f};

    const bf16x8* fragv = (const bf16x8*)frag;
    #pragma unroll
    for (int kt = 0; kt < 4; ++kt) {               // K = 128 over W_neigh (frag kt 4..7)
        int kb = kt * 32 + q * 8;
        bf16x8 a = *(const bf16x8*)(h + (size_t)rowA * 128 + kb);
        #pragma unroll
        for (int ct = 0; ct < 4; ++ct) {
            bf16x8 b = fragv[(ct * 8 + kt + 4) * 64 + lane];
            acc[ct] = __builtin_amdgcn_mfma_f32_16x16x32_bf16(a, b, acc[ct], 0, 0, 0);
        }
    }
    #pragma unroll
    for (int ct = 0; ct < 4; ++ct) {
        #pragma unroll
        for (int r = 0; r < 4; ++r) {
            int row = n0 + q * 4 + r;
            if (row < N_NODES)
                ((unsigned short*)t_out)[(size_t)row * 64 + ct * 16 + l15] = f2bf(acc[ct][r]);
        }
    }
}

// ---------------- layer-3 final: out = h2 @ W_self2 + g + b2 (fp32 out) ----------------
__global__ __launch_bounds__(256) void k_gemmS(const __hip_bfloat16* __restrict__ h,
                                               const __hip_bfloat16* __restrict__ frag,
                                               const float* __restrict__ bias,
                                               const float* __restrict__ g,
                                               float* __restrict__ out) {
    int tid = threadIdx.x;
    int wv = tid >> 6, lane = tid & 63;
    int n0 = blockIdx.x * 64 + wv * 16;
    if (n0 >= N_NODES) return;
    int q = lane >> 4, l15 = lane & 15;
    int rowA = n0 + l15;
    if (rowA > N_NODES - 1) rowA = N_NODES - 1;

    f32x4 acc[4];
    #pragma unroll
    for (int c = 0; c < 4; ++c) acc[c] = (f32x4){0.f, 0.f, 0.f, 0.f};

    const bf16x8* fragv = (const bf16x8*)frag;
    #pragma unroll
    for (int kt = 0; kt < 4; ++kt) {               // K = 128 over W_self (frag kt 0..3)
        int kb = kt * 32 + q * 8;
        bf16x8 a = *(const bf16x8*)(h + (size_t)rowA * 128 + kb);
        #pragma unroll
        for (int ct = 0; ct < 4; ++ct) {
            bf16x8 b = fragv[(ct * 8 + kt) * 64 + lane];
            acc[ct] = __builtin_amdgcn_mfma_f32_16x16x32_bf16(a, b, acc[ct], 0, 0, 0);
        }
    }
    #pragma unroll
    for (int ct = 0; ct < 4; ++ct) {
        float bc = bias[ct * 16 + l15];
        #pragma unroll
        for (int r = 0; r < 4; ++r) {
            int row = n0 + q * 4 + r;
            if (row < N_NODES) {
                float v = acc[ct][r] + bc + g[(size_t)row * 64 + ct * 16 + l15];
                out[(size_t)row * 64 + ct * 16 + l15] = v;
            }
        }
    }
}

// ---------------- host launch ----------------

extern "C" void kernel_launch(void* const* d_in, const int* in_sizes, int n_in,
                              void* d_out, int out_size, void* d_ws, size_t ws_size,
                              hipStream_t stream) {
    const float* features = (const float*)d_in[0];
    const int* src = (const int*)d_in[1];
    const int* dst = (const int*)d_in[2];
    const float* Ws0 = (const float*)d_in[3];
    const float* Wn0 = (const float*)d_in[4];
    const float* b0  = (const float*)d_in[5];
    const float* Ws1 = (const float*)d_in[6];
    const float* Wn1 = (const float*)d_in[7];
    const float* b1  = (const float*)d_in[8];
    const float* Ws2 = (const float*)d_in[9];
    const float* Wn2 = (const float*)d_in[10];
    const float* b2  = (const float*)d_in[11];
    float* out = (float*)d_out;

    char* ws = (char*)d_ws;
    size_t off = 0;
    auto alloc = [&](size_t bytes) -> void* {
        void* p = ws + off;
        off = (off + bytes + 255) & ~(size_t)255;
        return p;
    };
    int*   deg      = (int*)alloc((size_t)N_NODES * 4);
    int*   off_beg  = (int*)alloc((size_t)N_NODES * 4);
    int*   off_end  = (int*)alloc((size_t)N_NODES * 4);
    int*   edge_src = (int*)alloc((size_t)N_NODES * SLOTS * 4);
    float* inv_deg  = (float*)alloc((size_t)N_NODES * 4);
    __hip_bfloat16* fbf = (__hip_bfloat16*)alloc((size_t)(N_NODES + 1) * 128 * 2);
    __hip_bfloat16* msg = (__hip_bfloat16*)alloc((size_t)N_NODES * 128 * 2);
    __hip_bfloat16* h1  = (__hip_bfloat16*)alloc((size_t)(N_NODES + 1) * 128 * 2);
    __hip_bfloat16* h2  = (__hip_bfloat16*)alloc((size_t)(N_NODES + 1) * 128 * 2);
    __hip_bfloat16* t2  = (__hip_bfloat16*)alloc((size_t)(N_NODES + 1) * 64 * 2);
    float* g   = (float*)alloc((size_t)N_NODES * 64 * 4);
    __hip_bfloat16* frag0 = (__hip_bfloat16*)alloc((size_t)8 * 8 * 64 * 8 * 2);
    __hip_bfloat16* frag1 = (__hip_bfloat16*)alloc((size_t)8 * 8 * 64 * 8 * 2);
    __hip_bfloat16* frag2 = (__hip_bfloat16*)alloc((size_t)4 * 8 * 64 * 8 * 2);

    // prep (frags + f2bf + zero-rows + slot prefill + deg zero), then direct CSR
    const int prepGrid = 40 + NF2 + 1 + FILL_BLOCKS + DEG_BLOCKS;  // 5706
    k_prep<<<prepGrid, 256, 0, stream>>>(Ws0, Wn0, Ws1, Wn1, Ws2, Wn2,
                                         frag0, frag1, frag2,
                                         features, (unsigned int*)fbf,
                                         (unsigned int*)h1, (unsigned int*)h2,
                                         (unsigned int*)t2,
                                         edge_src, deg);
    k_scatter<<<(N_EDGES + 255) / 256, 256, 0, stream>>>(src, dst, deg, edge_src);
    k_nodes<<<DEG_BLOCKS, 256, 0, stream>>>(deg, off_beg, off_end, inv_deg);

    const int aggGrid = (N_NODES * 64) / 256;  // 12500
    const int gemmGrid = (N_NODES + 63) / 64;  // 782

    // Layer 1
    k_agg<<<aggGrid, 256, 0, stream>>>(fbf, off_beg, off_end, edge_src, inv_deg, msg);
    k_gemm<8, false><<<gemmGrid, 256, 0, stream>>>(fbf, msg, frag0, b0, h1);
    // Layer 2
    k_agg<<<aggGrid, 256, 0, stream>>>(h1, off_beg, off_end, edge_src, inv_deg, msg);
    k_gemm<8, false><<<gemmGrid, 256, 0, stream>>>(h1, msg, frag1, b1, h2);
    // Layer 3: transform-first (mean commutes with the linear map) -> 128B gathers
    k_gemmT<<<gemmGrid, 256, 0, stream>>>(h2, frag2, t2);
    k_agg64<<<aggGrid, 256, 0, stream>>>(t2, off_beg, off_end, edge_src, inv_deg, g);
    k_gemmS<<<gemmGrid, 256, 0, stream>>>(h2, frag2, b2, g, out);
}

// Round 13
// 248.777 us; speedup vs baseline: 1.1156x; 1.1156x over previous
//
#include <hip/hip_runtime.h>
#include <hip/hip_bf16.h>

#define N_NODES 50000
#define N_EDGES 800000
#define NBUCKET 196        // NPB=256: bucket = dst>>8, local = dst&255
#define NPB 256
#define BUCKET_CAP 7168    // raw bucket occupancy ~6470 mean; padded-CSR total ~5965 mean; 9+ sigma margin
#define BUCKET_PAD 8192    // fixed per-bucket region in edge_src (padded layout), no scan needed
#define PART_EDGES 4096
#define PART_BLOCKS ((N_EDGES + PART_EDGES - 1) / PART_EDGES)  // 196
#define SENTINEL 0xFFFFFFFFu

typedef __attribute__((ext_vector_type(8))) short bf16x8;
typedef __attribute__((ext_vector_type(4))) float f32x4;

__device__ __forceinline__ float bf2f(unsigned short u) {
    unsigned int x = ((unsigned int)u) << 16;
    return __uint_as_float(x);
}
__device__ __forceinline__ unsigned short f2bf(float f) {
    unsigned int x = __float_as_uint(f);
    unsigned int lsb = (x >> 16) & 1u;
    x += 0x7fffu + lsb;
    return (unsigned short)(x >> 16);
}
__device__ __forceinline__ unsigned int packbf(float lo, float hi) {
    return ((unsigned int)f2bf(hi) << 16) | (unsigned int)f2bf(lo);
}

// ---------------- prep: W fragments + features->bf16 (uint4-vectorized) + zero counters/rows ----------------
#define NF2 3125   // 800000 uint4 conversions / 256
__global__ __launch_bounds__(256) void k_prep(
        const float* __restrict__ Ws0, const float* __restrict__ Wn0,
        const float* __restrict__ Ws1, const float* __restrict__ Wn1,
        const float* __restrict__ Ws2, const float* __restrict__ Wn2,
        __hip_bfloat16* __restrict__ frag0, __hip_bfloat16* __restrict__ frag1,
        __hip_bfloat16* __restrict__ frag2,
        const float* __restrict__ fin, unsigned int* __restrict__ fout,
        unsigned int* __restrict__ z1, unsigned int* __restrict__ z2,
        unsigned int* __restrict__ zt,
        int* __restrict__ cursor, int* __restrict__ valid) {
    int b = blockIdx.x;
    if (b >= 40 + NF2) {  // zero bucket counters + gather zero-rows (row N_NODES of fbf,h1,h2,t2)
        int tid = threadIdx.x;
        if (tid < NBUCKET) { cursor[tid] = 0; valid[tid] = 0; }
        if (tid < 64)       fout[(size_t)N_NODES * 64 + tid] = 0;
        else if (tid < 128) z1[(size_t)N_NODES * 64 + (tid - 64)] = 0;
        else if (tid < 192) z2[(size_t)N_NODES * 64 + (tid - 128)] = 0;
        else if (tid < 224) zt[(size_t)N_NODES * 32 + (tid - 192)] = 0;  // t2 row (64 bf16)
        return;
    }
    if (b >= 40) {  // features fp32 -> bf16, 8 floats -> uint4 per thread
        int i = (b - 40) * 256 + threadIdx.x;   // i < 800000
        const float4* f4 = (const float4*)fin;
        float4 a = f4[2 * i];
        float4 c = f4[2 * i + 1];
        uint4 o;
        o.x = packbf(a.x, a.y);
        o.y = packbf(a.z, a.w);
        o.z = packbf(c.x, c.y);
        o.w = packbf(c.z, c.w);
        ((uint4*)fout)[i] = o;
        return;
    }
    const float* Wself;
    const float* Wneigh;
    __hip_bfloat16* frag;
    int Dout, lb;
    if (b < 16)      { Wself = Ws0; Wneigh = Wn0; frag = frag0; Dout = 128; lb = b; }
    else if (b < 32) { Wself = Ws1; Wneigh = Wn1; frag = frag1; Dout = 128; lb = b - 16; }
    else             { Wself = Ws2; Wneigh = Wn2; frag = frag2; Dout = 64;  lb = b - 32; }
    int t = lb * 256 + threadIdx.x;
    int nCt = Dout >> 4;
    int total = nCt * 8 * 64;
    if (t >= total) return;
    int lane = t & 63;
    int kt = (t >> 6) & 7;
    int ct = t >> 9;
    int q = lane >> 4;
    int n = ct * 16 + (lane & 15);
    unsigned short* dstp = (unsigned short*)frag + ((size_t)((ct * 8 + kt) * 64 + lane)) * 8;
    #pragma unroll
    for (int j = 0; j < 8; ++j) {
        int k = kt * 32 + q * 8 + j;
        float v = (k < 128) ? Wself[k * Dout + n] : Wneigh[(k - 128) * Dout + n];
        dstp[j] = f2bf(v);
    }
}

// ---------------- bucketed CSR build: 1024-thread blocks for latency hiding ----------------
__global__ __launch_bounds__(1024) void k_partA(const int* __restrict__ src,
                                                const int* __restrict__ dst,
                                                int* __restrict__ cursor,
                                                int* __restrict__ valid,
                                                unsigned int* __restrict__ bucketArr) {
    __shared__ int hist[NBUCKET];
    __shared__ int base[NBUCKET];
    __shared__ int cnt[NBUCKET];
    int tid = threadIdx.x;
    if (tid < NBUCKET) hist[tid] = 0;
    __syncthreads();
    int e0 = blockIdx.x * PART_EDGES;
    for (int j = 0; j < PART_EDGES; j += 1024) {
        int e = e0 + j + tid;
        if (e < N_EDGES) atomicAdd(&hist[dst[e] >> 8], 1);
    }
    __syncthreads();
    if (tid < NBUCKET) {
        int h = hist[tid];
        int hp = (h + 15) & ~15;  // 64B-aligned reservation
        int b0 = atomicAdd(&cursor[tid], hp);
        atomicAdd(&valid[tid], h);
        base[tid] = b0;
        cnt[tid] = 0;
        for (int k = h; k < hp; ++k) {  // sentinel-fill our own padding slots
            int p = b0 + k;
            if (p < BUCKET_CAP) bucketArr[(size_t)tid * BUCKET_CAP + p] = SENTINEL;
        }
    }
    __syncthreads();
    for (int j = 0; j < PART_EDGES; j += 1024) {
        int e = e0 + j + tid;
        if (e < N_EDGES) {
            int d = dst[e];
            int b = d >> 8;
            int p = base[b] + atomicAdd(&cnt[b], 1);
            if (p < BUCKET_CAP)
                bucketArr[(size_t)b * BUCKET_CAP + p] =
                    (unsigned int)src[e] | ((unsigned int)(d & 255) << 16);
        }
    }
}

// Phase B: one 1024-thread block per bucket; LDS-local CSR with PER-NODE 16-padding (pad
// slots -> zero row N_NODES). Bucket b owns edge_src[b*BUCKET_PAD..+BUCKET_PAD). Wave scan.
__global__ __launch_bounds__(1024) void k_partB(const unsigned int* __restrict__ bucketArr,
                                                const int* __restrict__ cursor,
                                                int* __restrict__ off_beg,
                                                int* __restrict__ off_end,
                                                float* __restrict__ inv_deg,
                                                int* __restrict__ edge_src) {
    __shared__ unsigned int ed[BUCKET_CAP];
    __shared__ int csr[BUCKET_CAP];
    __shared__ int hist[256];
    __shared__ int lbase[256];
    __shared__ int lcnt[256];
    __shared__ int wsum[4];
    int b = blockIdx.x;
    int tid = threadIdx.x;
    int size = min(cursor[b], BUCKET_CAP);
    int B0 = b * BUCKET_PAD;
    int nbase = b * NPB;
    int ncount = min(NPB, N_NODES - nbase);
    if (tid < 256) hist[tid] = 0;
    __syncthreads();
    for (int j = 0; j < BUCKET_CAP; j += 1024) {
        int i = j + tid;
        if (i < size) {
            unsigned int u = bucketArr[(size_t)b * BUCKET_CAP + i];
            ed[i] = u;
            if ((u >> 16) < 256u) atomicAdd(&hist[u >> 16], 1);  // skip sentinels
        }
    }
    __syncthreads();
    int v = 0, pv = 0;
    if (tid < 256) { v = hist[tid]; pv = (v + 15) & ~15; }   // padded degree
    // wave-level inclusive scan of pv (waves 0..3 cover the 256 nodes)
    int x = pv;
    #pragma unroll
    for (int d = 1; d < 64; d <<= 1) {
        int y = __shfl_up(x, d);
        if ((tid & 63) >= d) x += y;
    }
    if (tid < 256 && (tid & 63) == 63) wsum[tid >> 6] = x;
    __syncthreads();
    int wid = tid >> 6;
    int prefix = 0;
    #pragma unroll
    for (int w2 = 0; w2 < 4; ++w2)
        if (w2 < wid) prefix += wsum[w2];
    int excl = prefix + x - pv;        // exclusive scan of padded degrees (valid for tid<256)
    int tot = min(wsum[0] + wsum[1] + wsum[2] + wsum[3], BUCKET_CAP);
    if (tid < 256) {
        lbase[tid] = excl;
        lcnt[tid] = 0;
        if (tid < ncount) {
            off_beg[nbase + tid] = B0 + excl;
            off_end[nbase + tid] = B0 + excl + pv;          // PADDED end (multiple of 16 span)
            inv_deg[nbase + tid] = 1.0f / (float)max(v, 1); // real degree for the mean
        }
        // fill only OUR pad slots with the zero-row index (union over threads covers all pads)
        for (int p = excl + v; p < excl + pv; ++p)
            if (p < BUCKET_CAP) csr[p] = N_NODES;
    }
    __syncthreads();
    for (int j = 0; j < BUCKET_CAP; j += 1024) {
        int i = j + tid;
        if (i < size) {
            unsigned int u = ed[i];
            unsigned int ld = u >> 16;
            if (ld < 256u) {
                int p = lbase[ld] + atomicAdd(&lcnt[ld], 1);
                if (p < BUCKET_CAP) csr[p] = (int)(u & 0xffffu);
            }
        }
    }
    __syncthreads();
    for (int j = tid; j < tot; j += 1024) edge_src[B0 + j] = csr[j];
}

// ---------------- mean aggregation, 128-dim rows (R2-verified: 31.1 µs/launch) ----------------
__global__ void k_agg(const __hip_bfloat16* __restrict__ hv,
                      const int* __restrict__ off_beg, const int* __restrict__ off_end,
                      const int* __restrict__ edge_src, const float* __restrict__ inv_deg,
                      __hip_bfloat16* __restrict__ msg) {
    int gid = blockIdx.x * blockDim.x + threadIdx.x;
    int node = gid >> 6;
    int lane = gid & 63;
    if (node >= N_NODES) return;
    int quad = lane >> 4;   // which edge within a group of 4
    int sub = lane & 15;    // 16B column chunk
    int beg = off_beg[node], endp = off_end[node];  // span multiple of 16
    const uint4* hp = (const uint4*)hv;  // 16 uint4 per row

    float a0[8], a1[8], a2[8], a3[8];
    #pragma unroll
    for (int c = 0; c < 8; ++c) { a0[c] = 0.f; a1[c] = 0.f; a2[c] = 0.f; a3[c] = 0.f; }

    for (int i = beg; i < endp; i += 16) {
        int s0 = edge_src[i + quad];
        int s1 = edge_src[i + 4 + quad];
        int s2 = edge_src[i + 8 + quad];
        int s3 = edge_src[i + 12 + quad];
        uint4 u0 = hp[(size_t)s0 * 16 + sub];
        uint4 u1 = hp[(size_t)s1 * 16 + sub];
        uint4 u2 = hp[(size_t)s2 * 16 + sub];
        uint4 u3 = hp[(size_t)s3 * 16 + sub];
        a0[0] += bf2f((unsigned short)(u0.x & 0xffffu)); a0[1] += bf2f((unsigned short)(u0.x >> 16));
        a0[2] += bf2f((unsigned short)(u0.y & 0xffffu)); a0[3] += bf2f((unsigned short)(u0.y >> 16));
        a0[4] += bf2f((unsigned short)(u0.z & 0xffffu)); a0[5] += bf2f((unsigned short)(u0.z >> 16));
        a0[6] += bf2f((unsigned short)(u0.w & 0xffffu)); a0[7] += bf2f((unsigned short)(u0.w >> 16));
        a1[0] += bf2f((unsigned short)(u1.x & 0xffffu)); a1[1] += bf2f((unsigned short)(u1.x >> 16));
        a1[2] += bf2f((unsigned short)(u1.y & 0xffffu)); a1[3] += bf2f((unsigned short)(u1.y >> 16));
        a1[4] += bf2f((unsigned short)(u1.z & 0xffffu)); a1[5] += bf2f((unsigned short)(u1.z >> 16));
        a1[6] += bf2f((unsigned short)(u1.w & 0xffffu)); a1[7] += bf2f((unsigned short)(u1.w >> 16));
        a2[0] += bf2f((unsigned short)(u2.x & 0xffffu)); a2[1] += bf2f((unsigned short)(u2.x >> 16));
        a2[2] += bf2f((unsigned short)(u2.y & 0xffffu)); a2[3] += bf2f((unsigned short)(u2.y >> 16));
        a2[4] += bf2f((unsigned short)(u2.z & 0xffffu)); a2[5] += bf2f((unsigned short)(u2.z >> 16));
        a2[6] += bf2f((unsigned short)(u2.w & 0xffffu)); a2[7] += bf2f((unsigned short)(u2.w >> 16));
        a3[0] += bf2f((unsigned short)(u3.x & 0xffffu)); a3[1] += bf2f((unsigned short)(u3.x >> 16));
        a3[2] += bf2f((unsigned short)(u3.y & 0xffffu)); a3[3] += bf2f((unsigned short)(u3.y >> 16));
        a3[4] += bf2f((unsigned short)(u3.z & 0xffffu)); a3[5] += bf2f((unsigned short)(u3.z >> 16));
        a3[6] += bf2f((unsigned short)(u3.w & 0xffffu)); a3[7] += bf2f((unsigned short)(u3.w >> 16));
    }

    float r[8];
    #pragma unroll
    for (int c = 0; c < 8; ++c) {
        float t = a0[c] + a1[c] + a2[c] + a3[c];
        t += __shfl_xor(t, 16);
        t += __shfl_xor(t, 32);
        r[c] = t;
    }
    if (quad == 0) {
        float w = inv_deg[node];
        uint4 o;
        o.x = ((unsigned int)f2bf(r[1] * w) << 16) | (unsigned int)f2bf(r[0] * w);
        o.y = ((unsigned int)f2bf(r[3] * w) << 16) | (unsigned int)f2bf(r[2] * w);
        o.z = ((unsigned int)f2bf(r[5] * w) << 16) | (unsigned int)f2bf(r[4] * w);
        o.w = ((unsigned int)f2bf(r[7] * w) << 16) | (unsigned int)f2bf(r[6] * w);
        ((uint4*)msg)[(size_t)node * 16 + sub] = o;
    }
}

// ---------------- mean aggregation, 64-dim rows (layer 3 transform-first) ----------------
__global__ void k_agg64(const __hip_bfloat16* __restrict__ tv,
                        const int* __restrict__ off_beg, const int* __restrict__ off_end,
                        const int* __restrict__ edge_src, const float* __restrict__ inv_deg,
                        float* __restrict__ g) {
    int gid = blockIdx.x * blockDim.x + threadIdx.x;
    int node = gid >> 6;
    int lane = gid & 63;
    if (node >= N_NODES) return;
    int oct = lane >> 3;    // edge slot 0..7
    int sub8 = lane & 7;    // 16B chunk within 128B row
    int beg = off_beg[node], endp = off_end[node];  // span multiple of 16
    const uint4* tp = (const uint4*)tv;  // 8 uint4 per 128B row

    float a0[8], a1[8];
    #pragma unroll
    for (int c = 0; c < 8; ++c) { a0[c] = 0.f; a1[c] = 0.f; }

    for (int i = beg; i < endp; i += 16) {
        int s0 = edge_src[i + oct];
        int s1 = edge_src[i + 8 + oct];
        uint4 u0 = tp[(size_t)s0 * 8 + sub8];
        uint4 u1 = tp[(size_t)s1 * 8 + sub8];
        a0[0] += bf2f((unsigned short)(u0.x & 0xffffu)); a0[1] += bf2f((unsigned short)(u0.x >> 16));
        a0[2] += bf2f((unsigned short)(u0.y & 0xffffu)); a0[3] += bf2f((unsigned short)(u0.y >> 16));
        a0[4] += bf2f((unsigned short)(u0.z & 0xffffu)); a0[5] += bf2f((unsigned short)(u0.z >> 16));
        a0[6] += bf2f((unsigned short)(u0.w & 0xffffu)); a0[7] += bf2f((unsigned short)(u0.w >> 16));
        a1[0] += bf2f((unsigned short)(u1.x & 0xffffu)); a1[1] += bf2f((unsigned short)(u1.x >> 16));
        a1[2] += bf2f((unsigned short)(u1.y & 0xffffu)); a1[3] += bf2f((unsigned short)(u1.y >> 16));
        a1[4] += bf2f((unsigned short)(u1.z & 0xffffu)); a1[5] += bf2f((unsigned short)(u1.z >> 16));
        a1[6] += bf2f((unsigned short)(u1.w & 0xffffu)); a1[7] += bf2f((unsigned short)(u1.w >> 16));
    }

    float r[8];
    #pragma unroll
    for (int c = 0; c < 8; ++c) {
        float t = a0[c] + a1[c];
        t += __shfl_xor(t, 8);    // reduce over the 8 oct groups (lane bits 3..5)
        t += __shfl_xor(t, 16);
        t += __shfl_xor(t, 32);
        r[c] = t;
    }
    if (oct == 0) {  // lanes 0..7 each write 8 fp32 (their 16B bf16 chunk -> 32B fp32)
        float w = inv_deg[node];
        float4 o1 = {r[0] * w, r[1] * w, r[2] * w, r[3] * w};
        float4 o2 = {r[4] * w, r[5] * w, r[6] * w, r[7] * w};
        ((float4*)g)[(size_t)node * 16 + sub8 * 2]     = o1;
        ((float4*)g)[(size_t)node * 16 + sub8 * 2 + 1] = o2;
    }
}

// ---------------- fused GEMM + bias (+ relu + l2norm), layers 1-2 ----------------
template <int NCT, bool LAST>
__global__ __launch_bounds__(256) void k_gemm(const __hip_bfloat16* __restrict__ Aself,
                                              const __hip_bfloat16* __restrict__ Aneigh,
                                              const __hip_bfloat16* __restrict__ frag,
                                              const float* __restrict__ bias,
                                              void* __restrict__ out_) {
    constexpr int Dout = NCT * 16;
    int tid = threadIdx.x;
    int wv = tid >> 6, lane = tid & 63;
    int n0 = blockIdx.x * 64 + wv * 16;
    if (n0 >= N_NODES) return;
    int q = lane >> 4, l15 = lane & 15;
    int rowA = n0 + l15;
    if (rowA > N_NODES - 1) rowA = N_NODES - 1;

    f32x4 acc[NCT];
    #pragma unroll
    for (int c = 0; c < NCT; ++c) acc[c] = (f32x4){0.f, 0.f, 0.f, 0.f};

    const bf16x8* fragv = (const bf16x8*)frag;
    #pragma unroll
    for (int kt = 0; kt < 8; ++kt) {
        int kb = (kt & 3) * 32 + q * 8;
        const __hip_bfloat16* Ab = (kt < 4) ? Aself : Aneigh;
        bf16x8 a = *(const bf16x8*)(Ab + (size_t)rowA * 128 + kb);
        #pragma unroll
        for (int ct = 0; ct < NCT; ++ct) {
            bf16x8 b = fragv[(ct * 8 + kt) * 64 + lane];
            acc[ct] = __builtin_amdgcn_mfma_f32_16x16x32_bf16(a, b, acc[ct], 0, 0, 0);
        }
    }

    float ss[4] = {0.f, 0.f, 0.f, 0.f};
    #pragma unroll
    for (int ct = 0; ct < NCT; ++ct) {
        float bc = bias[ct * 16 + l15];
        #pragma unroll
        for (int r = 0; r < 4; ++r) {
            float v = acc[ct][r] + bc;
            if (!LAST) v = fmaxf(v, 0.0f);
            acc[ct][r] = v;
            ss[r] += v * v;
        }
    }

    float scale[4];
    #pragma unroll
    for (int r = 0; r < 4; ++r) {
        if (!LAST) {
            float s = ss[r];
            s += __shfl_xor(s, 1);
            s += __shfl_xor(s, 2);
            s += __shfl_xor(s, 4);
            s += __shfl_xor(s, 8);
            scale[r] = 1.0f / fmaxf(sqrtf(s), 1e-12f);
        } else {
            scale[r] = 1.0f;
        }
    }

    #pragma unroll
    for (int ct = 0; ct < NCT; ++ct) {
        #pragma unroll
        for (int r = 0; r < 4; ++r) {
            int row = n0 + q * 4 + r;
            if (row < N_NODES) {
                float v = acc[ct][r] * scale[r];
                if (LAST)
                    ((float*)out_)[(size_t)row * Dout + ct * 16 + l15] = v;
                else
                    ((unsigned short*)out_)[(size_t)row * Dout + ct * 16 + l15] = f2bf(v);
            }
        }
    }
}

// ---------------- layer-3 pre-transform: t2 = h2 @ W_neigh2 (bf16 out, no epilogue) ----------------
__global__ __launch_bounds__(256) void k_gemmT(const __hip_bfloat16* __restrict__ h,
                                               const __hip_bfloat16* __restrict__ frag,
                                               __hip_bfloat16* __restrict__ t_out) {
    int tid = threadIdx.x;
    int wv = tid >> 6, lane = tid & 63;
    int n0 = blockIdx.x * 64 + wv * 16;
    if (n0 >= N_NODES) return;
    int q = lane >> 4, l15 = lane & 15;
    int rowA = n0 + l15;
    if (rowA > N_NODES - 1) rowA = N_NODES - 1;

    f32x4 acc[4];
    #pragma unroll
    for (int c = 0; c < 4; ++c) acc[c] = (f32x4){0.f, 0.f, 0.f, 0.f};

    const bf16x8* fragv = (const bf16x8*)frag;
    #pragma unroll
    for (int kt = 0; kt < 4; ++kt) {               // K = 128 over W_neigh (frag kt 4..7)
        int kb = kt * 32 + q * 8;
        bf16x8 a = *(const bf16x8*)(h + (size_t)rowA * 128 + kb);
        #pragma unroll
        for (int ct = 0; ct < 4; ++ct) {
            bf16x8 b = fragv[(ct * 8 + kt + 4) * 64 + lane];
            acc[ct] = __builtin_amdgcn_mfma_f32_16x16x32_bf16(a, b, acc[ct], 0, 0, 0);
        }
    }
    #pragma unroll
    for (int ct = 0; ct < 4; ++ct) {
        #pragma unroll
        for (int r = 0; r < 4; ++r) {
            int row = n0 + q * 4 + r;
            if (row < N_NODES)
                ((unsigned short*)t_out)[(size_t)row * 64 + ct * 16 + l15] = f2bf(acc[ct][r]);
        }
    }
}

// ---------------- layer-3 final: out = h2 @ W_self2 + g + b2 (fp32 out) ----------------
__global__ __launch_bounds__(256) void k_gemmS(const __hip_bfloat16* __restrict__ h,
                                               const __hip_bfloat16* __restrict__ frag,
                                               const float* __restrict__ bias,
                                               const float* __restrict__ g,
                                               float* __restrict__ out) {
    int tid = threadIdx.x;
    int wv = tid >> 6, lane = tid & 63;
    int n0 = blockIdx.x * 64 + wv * 16;
    if (n0 >= N_NODES) return;
    int q = lane >> 4, l15 = lane & 15;
    int rowA = n0 + l15;
    if (rowA > N_NODES - 1) rowA = N_NODES - 1;

    f32x4 acc[4];
    #pragma unroll
    for (int c = 0; c < 4; ++c) acc[c] = (f32x4){0.f, 0.f, 0.f, 0.f};

    const bf16x8* fragv = (const bf16x8*)frag;
    #pragma unroll
    for (int kt = 0; kt < 4; ++kt) {               // K = 128 over W_self (frag kt 0..3)
        int kb = kt * 32 + q * 8;
        bf16x8 a = *(const bf16x8*)(h + (size_t)rowA * 128 + kb);
        #pragma unroll
        for (int ct = 0; ct < 4; ++ct) {
            bf16x8 b = fragv[(ct * 8 + kt) * 64 + lane];
            acc[ct] = __builtin_amdgcn_mfma_f32_16x16x32_bf16(a, b, acc[ct], 0, 0, 0);
        }
    }
    #pragma unroll
    for (int ct = 0; ct < 4; ++ct) {
        float bc = bias[ct * 16 + l15];
        #pragma unroll
        for (int r = 0; r < 4; ++r) {
            int row = n0 + q * 4 + r;
            if (row < N_NODES) {
                float v = acc[ct][r] + bc + g[(size_t)row * 64 + ct * 16 + l15];
                out[(size_t)row * 64 + ct * 16 + l15] = v;
            }
        }
    }
}

// ---------------- host launch ----------------

extern "C" void kernel_launch(void* const* d_in, const int* in_sizes, int n_in,
                              void* d_out, int out_size, void* d_ws, size_t ws_size,
                              hipStream_t stream) {
    const float* features = (const float*)d_in[0];
    const int* src = (const int*)d_in[1];
    const int* dst = (const int*)d_in[2];
    const float* Ws0 = (const float*)d_in[3];
    const float* Wn0 = (const float*)d_in[4];
    const float* b0  = (const float*)d_in[5];
    const float* Ws1 = (const float*)d_in[6];
    const float* Wn1 = (const float*)d_in[7];
    const float* b1  = (const float*)d_in[8];
    const float* Ws2 = (const float*)d_in[9];
    const float* Wn2 = (const float*)d_in[10];
    const float* b2  = (const float*)d_in[11];
    float* out = (float*)d_out;

    char* ws = (char*)d_ws;
    size_t off = 0;
    auto alloc = [&](size_t bytes) -> void* {
        void* p = ws + off;
        off = (off + bytes + 255) & ~(size_t)255;
        return p;
    };
    int*   cursor   = (int*)alloc((size_t)NBUCKET * 4);
    int*   valid    = (int*)alloc((size_t)NBUCKET * 4);
    unsigned int* bucketArr = (unsigned int*)alloc((size_t)NBUCKET * BUCKET_CAP * 4);
    int*   off_beg  = (int*)alloc((size_t)N_NODES * 4);
    int*   off_end  = (int*)alloc((size_t)N_NODES * 4);
    int*   edge_src = (int*)alloc((size_t)NBUCKET * BUCKET_PAD * 4);
    float* inv_deg  = (float*)alloc((size_t)N_NODES * 4);
    __hip_bfloat16* fbf = (__hip_bfloat16*)alloc((size_t)(N_NODES + 1) * 128 * 2);
    __hip_bfloat16* msg = (__hip_bfloat16*)alloc((size_t)N_NODES * 128 * 2);
    __hip_bfloat16* h1  = (__hip_bfloat16*)alloc((size_t)(N_NODES + 1) * 128 * 2);
    __hip_bfloat16* h2  = (__hip_bfloat16*)alloc((size_t)(N_NODES + 1) * 128 * 2);
    __hip_bfloat16* t2  = (__hip_bfloat16*)alloc((size_t)(N_NODES + 1) * 64 * 2);
    float* g   = (float*)alloc((size_t)N_NODES * 64 * 4);
    __hip_bfloat16* frag0 = (__hip_bfloat16*)alloc((size_t)8 * 8 * 64 * 8 * 2);
    __hip_bfloat16* frag1 = (__hip_bfloat16*)alloc((size_t)8 * 8 * 64 * 8 * 2);
    __hip_bfloat16* frag2 = (__hip_bfloat16*)alloc((size_t)4 * 8 * 64 * 8 * 2);

    // prep (frags + f2bf + counter/zero-row init), then bucketed CSR (1024-thread blocks)
    k_prep<<<40 + NF2 + 1, 256, 0, stream>>>(Ws0, Wn0, Ws1, Wn1, Ws2, Wn2,
                                             frag0, frag1, frag2,
                                             features, (unsigned int*)fbf,
                                             (unsigned int*)h1, (unsigned int*)h2,
                                             (unsigned int*)t2,
                                             cursor, valid);
    k_partA<<<PART_BLOCKS, 1024, 0, stream>>>(src, dst, cursor, valid, bucketArr);
    k_partB<<<NBUCKET, 1024, 0, stream>>>(bucketArr, cursor,
                                          off_beg, off_end, inv_deg, edge_src);

    const int aggGrid = (N_NODES * 64) / 256;  // 12500
    const int gemmGrid = (N_NODES + 63) / 64;  // 782

    // Layer 1
    k_agg<<<aggGrid, 256, 0, stream>>>(fbf, off_beg, off_end, edge_src, inv_deg, msg);
    k_gemm<8, false><<<gemmGrid, 256, 0, stream>>>(fbf, msg, frag0, b0, h1);
    // Layer 2
    k_agg<<<aggGrid, 256, 0, stream>>>(h1, off_beg, off_end, edge_src, inv_deg, msg);
    k_gemm<8, false><<<gemmGrid, 256, 0, stream>>>(h1, msg, frag1, b1, h2);
    // Layer 3: transform-first (mean commutes with the linear map) -> 128B gathers
    k_gemmT<<<gemmGrid, 256, 0, stream>>>(h2, frag2, t2);
    k_agg64<<<aggGrid, 256, 0, stream>>>(t2, off_beg, off_end, edge_src, inv_deg, g);
    k_gemmS<<<gemmGrid, 256, 0, stream>>>(h2, frag2, b2, g, out);
}